// Round 1
// baseline (1033.830 us; speedup 1.0000x reference)
//
#include <hip/hip_runtime.h>
#include <hip/hip_bf16.h>

#define D 64   // D_IN == D_OUT == 64

// ---------------------------------------------------------------------------
// k1: deg[i] = 1.0 (self-loop weight folded in)
__global__ __launch_bounds__(256) void gcn_deg_init(float* __restrict__ deg, int n) {
    int i = blockIdx.x * 256 + threadIdx.x;
    if (i < n) deg[i] = 1.0f;
}

// k2: deg[row[e]] += ew[e]
__global__ __launch_bounds__(256) void gcn_deg_scatter(const int* __restrict__ rowi,
                                                       const float* __restrict__ ew,
                                                       float* __restrict__ deg, int nE) {
    int e = blockIdx.x * 256 + threadIdx.x;
    if (e < nE) atomicAdd(&deg[rowi[e]], ew[e]);
}

// k3: dis[i] = rsqrt(deg[i]); agg[i][:] = x[i][:] / deg[i]  (self-loop message)
// one thread per (node, float4-group): g = i*16 + j
__global__ __launch_bounds__(256) void gcn_norm_init(const float* __restrict__ deg,
                                                     float* __restrict__ dis,
                                                     const float* __restrict__ x,
                                                     float* __restrict__ agg, int n) {
    int g = blockIdx.x * 256 + threadIdx.x;
    int i = g >> 4;
    if (i >= n) return;
    int j = g & 15;
    float d = deg[i];           // >= 1 always
    float inv = 1.0f / d;       // dis[i]^2 * ew(=1)
    if (j == 0) dis[i] = rsqrtf(d);
    float4 xv = ((const float4*)x)[g];
    float4 o;
    o.x = xv.x * inv; o.y = xv.y * inv; o.z = xv.z * inv; o.w = xv.w * inv;
    ((float4*)agg)[g] = o;
}

// k4: edge scatter. 16 lanes per edge, each lane handles a float4 of channels.
__global__ __launch_bounds__(256) void gcn_edge_scatter(const int* __restrict__ rowi,
                                                        const int* __restrict__ coli,
                                                        const float* __restrict__ ew,
                                                        const float* __restrict__ dis,
                                                        const float* __restrict__ x,
                                                        float* __restrict__ agg, int nE) {
    int g = blockIdx.x * 256 + threadIdx.x;
    int e = g >> 4;
    if (e >= nE) return;
    int j = g & 15;
    int r = rowi[e];
    int c = coli[e];
    float norm = dis[r] * ew[e] * dis[c];
    float4 xv = ((const float4*)x)[c * 16 + j];
    float* dst = agg + r * D + j * 4;
    atomicAdd(dst + 0, xv.x * norm);
    atomicAdd(dst + 1, xv.y * norm);
    atomicAdd(dst + 2, xv.z * norm);
    atomicAdd(dst + 3, xv.w * norm);
}

// k5: out = agg @ W^T + bias, 64-row tile/block, 4x4 register blocking.
// IN-PLACE safe (agg == out): each block stages its own 64 rows through LDS
// before writing those same rows back.
__global__ __launch_bounds__(256) void gcn_gemm(const float* __restrict__ agg,
                                                const float* __restrict__ W,
                                                const float* __restrict__ bias,
                                                float* __restrict__ out, int n) {
    // pad leading dim to 68: bank = (4k + r) % 32 -> max 2-way (free), 16B aligned
    __shared__ float Ast[D][68];  // Ast[k][r] = agg[r0+r][k]
    __shared__ float Bs[D][68];   // Bs[k][o]  = W[o][k]
    int tid = threadIdx.x;
    int r0 = blockIdx.x * 64;

    const float4* W4 = (const float4*)W;
    const float4* A4 = (const float4*)agg;
#pragma unroll
    for (int v = 0; v < 4; ++v) {
        int idx = tid + v * 256;          // 0..1023 float4 slots
        int a = idx >> 4;                 // row (A) / out-ch (W), 0..63
        int k0 = (idx & 15) * 4;          // k base
        // W tile (same for all blocks; L2-resident)
        float4 wv = W4[idx];
        Bs[k0 + 0][a] = wv.x; Bs[k0 + 1][a] = wv.y;
        Bs[k0 + 2][a] = wv.z; Bs[k0 + 3][a] = wv.w;
        // A tile
        int ra = r0 + a;
        float4 av = make_float4(0.f, 0.f, 0.f, 0.f);
        if (ra < n) av = A4[ra * 16 + (idx & 15)];
        Ast[k0 + 0][a] = av.x; Ast[k0 + 1][a] = av.y;
        Ast[k0 + 2][a] = av.z; Ast[k0 + 3][a] = av.w;
    }
    __syncthreads();

    int ty = tid >> 4;   // 0..15 -> rows ty*4..+4
    int tx = tid & 15;   // 0..15 -> cols tx*4..+4
    float acc[4][4];
#pragma unroll
    for (int m = 0; m < 4; ++m)
#pragma unroll
        for (int q = 0; q < 4; ++q) acc[m][q] = 0.f;

#pragma unroll
    for (int k = 0; k < D; ++k) {
        float4 a = *(const float4*)&Ast[k][ty * 4];
        float4 b = *(const float4*)&Bs[k][tx * 4];
        acc[0][0] += a.x * b.x; acc[0][1] += a.x * b.y; acc[0][2] += a.x * b.z; acc[0][3] += a.x * b.w;
        acc[1][0] += a.y * b.x; acc[1][1] += a.y * b.y; acc[1][2] += a.y * b.z; acc[1][3] += a.y * b.w;
        acc[2][0] += a.z * b.x; acc[2][1] += a.z * b.y; acc[2][2] += a.z * b.z; acc[2][3] += a.z * b.w;
        acc[3][0] += a.w * b.x; acc[3][1] += a.w * b.y; acc[3][2] += a.w * b.z; acc[3][3] += a.w * b.w;
    }

    float4 bv = *(const float4*)&bias[tx * 4];
    float4* out4 = (float4*)out;
#pragma unroll
    for (int m = 0; m < 4; ++m) {
        int r = r0 + ty * 4 + m;
        if (r < n) {
            float4 o;
            o.x = acc[m][0] + bv.x; o.y = acc[m][1] + bv.y;
            o.z = acc[m][2] + bv.z; o.w = acc[m][3] + bv.w;
            out4[r * 16 + tx] = o;
        }
    }
}

extern "C" void kernel_launch(void* const* d_in, const int* in_sizes, int n_in,
                              void* d_out, int out_size, void* d_ws, size_t ws_size,
                              hipStream_t stream) {
    const float* x    = (const float*)d_in[0];
    const int*   ei   = (const int*)d_in[1];   // [2*E] flat: rows then cols
    const float* ew   = (const float*)d_in[2];
    const float* W    = (const float*)d_in[3];
    const float* bias = (const float*)d_in[4];
    float* out = (float*)d_out;

    int n  = in_sizes[0] / D;   // 100000
    int nE = in_sizes[2];       // 1000000
    const int* rowi = ei;
    const int* coli = ei + nE;

    float* deg = (float*)d_ws;      // n floats
    float* dis = deg + n;           // n floats
    float* agg = out;               // in-place: aggregation buffer == output

    gcn_deg_init   <<<(n + 255) / 256, 256, 0, stream>>>(deg, n);
    gcn_deg_scatter<<<(nE + 255) / 256, 256, 0, stream>>>(rowi, ew, deg, nE);
    gcn_norm_init  <<<(n * 16 + 255) / 256, 256, 0, stream>>>(deg, dis, x, agg, n);
    gcn_edge_scatter<<<(nE * 16 + 255) / 256, 256, 0, stream>>>(rowi, coli, ew, dis, x, agg, nE);
    gcn_gemm       <<<(n + 63) / 64, 256, 0, stream>>>(agg, W, bias, out, n);
}

// Round 2
// 343.863 us; speedup vs baseline: 3.0065x; 3.0065x over previous
//
#include <hip/hip_runtime.h>
#include <hip/hip_bf16.h>

#define D 64   // D_IN == D_OUT == 64

// ---------------------------------------------------------------------------
// k1: deg[i]=1.0 (self-loop), cnt[i]=0, counter=0
__global__ __launch_bounds__(256) void k_init(float* __restrict__ deg,
                                              int* __restrict__ cnt,
                                              int* __restrict__ counter, int n) {
    int i = blockIdx.x * 256 + threadIdx.x;
    if (i < n) { deg[i] = 1.0f; cnt[i] = 0; }
    if (i == 0) *counter = 0;
}

// k2: per edge: deg[row] += ew; cnt[row] += 1   (2M scalar atomics)
__global__ __launch_bounds__(256) void k_count(const int* __restrict__ rowi,
                                               const float* __restrict__ ew,
                                               float* __restrict__ deg,
                                               int* __restrict__ cnt, int nE) {
    int e = blockIdx.x * 256 + threadIdx.x;
    if (e < nE) {
        int r = rowi[e];
        atomicAdd(&deg[r], ew[e]);
        atomicAdd(&cnt[r], 1);
    }
}

// k3: dis[i]=rsqrt(deg[i]); assign contiguous CSR segment per node.
// Wave-level exclusive scan of cnt -> ONE atomicAdd per wave on the global
// counter (1563 atomics instead of 100k serialized on one line).
__global__ __launch_bounds__(256) void k_dis_seg(const float* __restrict__ deg,
                                                 float* __restrict__ dis,
                                                 const int* __restrict__ cnt,
                                                 int* __restrict__ start,
                                                 int* __restrict__ pos,
                                                 int* __restrict__ counter, int n) {
    int i = blockIdx.x * 256 + threadIdx.x;
    int lane = threadIdx.x & 63;
    int c = (i < n) ? cnt[i] : 0;
    if (i < n) dis[i] = rsqrtf(deg[i]);
    // inclusive wave scan over 64 lanes
    int incl = c;
#pragma unroll
    for (int o = 1; o < 64; o <<= 1) {
        int t = __shfl_up(incl, o, 64);
        if (lane >= o) incl += t;
    }
    int total = __shfl(incl, 63, 64);
    int base = 0;
    if (lane == 0) base = atomicAdd(counter, total);
    base = __shfl(base, 0, 64);
    if (i < n) {
        int s = base + incl - c;   // exclusive
        start[i] = s;
        pos[i]   = s;
    }
}

// k4: place each edge into its row's segment; pack (col, ew*dis[col]) as int2.
__global__ __launch_bounds__(256) void k_place(const int* __restrict__ rowi,
                                               const int* __restrict__ coli,
                                               const float* __restrict__ ew,
                                               const float* __restrict__ dis,
                                               int* __restrict__ pos,
                                               int2* __restrict__ scw, int nE) {
    int e = blockIdx.x * 256 + threadIdx.x;
    if (e < nE) {
        int r = rowi[e];
        int c = coli[e];
        int p = atomicAdd(&pos[r], 1);
        int2 v;
        v.x = c;
        v.y = __float_as_int(ew[e] * dis[c]);
        scw[p] = v;
    }
}

// k5: gather-aggregate. 16 lanes per node, one float4 channel-slice per lane.
// agg[i] = x[i]/deg[i] + dis[i] * sum_e( w_e * x[col_e] )
__global__ __launch_bounds__(256) void k_gather(const float* __restrict__ x,
                                                const float* __restrict__ deg,
                                                const float* __restrict__ dis,
                                                const int* __restrict__ start,
                                                const int* __restrict__ cnt,
                                                const int2* __restrict__ scw,
                                                float* __restrict__ agg, int n) {
    int g = blockIdx.x * 256 + threadIdx.x;
    int i = g >> 4;
    if (i >= n) return;
    int j = g & 15;

    const float4* x4 = (const float4*)x;
    float4 acc = make_float4(0.f, 0.f, 0.f, 0.f);

    int s = start[i];
    int e_end = s + cnt[i];
    for (int e = s; e < e_end; ++e) {
        int2 v = scw[e];            // broadcast across the 16 lanes of node i
        float w = __int_as_float(v.y);
        float4 xv = x4[v.x * 16 + j];
        acc.x += w * xv.x; acc.y += w * xv.y;
        acc.z += w * xv.z; acc.w += w * xv.w;
    }

    float di  = dis[i];
    float inv = 1.0f / deg[i];      // self-loop: dis[i]*1*dis[i]
    float4 xs = x4[i * 16 + j];
    float4 o;
    o.x = xs.x * inv + di * acc.x;
    o.y = xs.y * inv + di * acc.y;
    o.z = xs.z * inv + di * acc.z;
    o.w = xs.w * inv + di * acc.w;
    ((float4*)agg)[i * 16 + j] = o;
}

// k6: out = agg @ W^T + bias, 64-row tile/block, 4x4 register blocking.
// IN-PLACE safe (agg == out): block stages its 64 rows through LDS first.
__global__ __launch_bounds__(256) void gcn_gemm(const float* __restrict__ agg,
                                                const float* __restrict__ W,
                                                const float* __restrict__ bias,
                                                float* __restrict__ out, int n) {
    __shared__ float Ast[D][68];  // Ast[k][r] = agg[r0+r][k]  (68: 2-way max, free)
    __shared__ float Bs[D][68];   // Bs[k][o]  = W[o][k]
    int tid = threadIdx.x;
    int r0 = blockIdx.x * 64;

    const float4* W4 = (const float4*)W;
    const float4* A4 = (const float4*)agg;
#pragma unroll
    for (int v = 0; v < 4; ++v) {
        int idx = tid + v * 256;
        int a = idx >> 4;
        int k0 = (idx & 15) * 4;
        float4 wv = W4[idx];
        Bs[k0 + 0][a] = wv.x; Bs[k0 + 1][a] = wv.y;
        Bs[k0 + 2][a] = wv.z; Bs[k0 + 3][a] = wv.w;
        int ra = r0 + a;
        float4 av = make_float4(0.f, 0.f, 0.f, 0.f);
        if (ra < n) av = A4[ra * 16 + (idx & 15)];
        Ast[k0 + 0][a] = av.x; Ast[k0 + 1][a] = av.y;
        Ast[k0 + 2][a] = av.z; Ast[k0 + 3][a] = av.w;
    }
    __syncthreads();

    int ty = tid >> 4;
    int tx = tid & 15;
    float acc[4][4];
#pragma unroll
    for (int m = 0; m < 4; ++m)
#pragma unroll
        for (int q = 0; q < 4; ++q) acc[m][q] = 0.f;

#pragma unroll
    for (int k = 0; k < D; ++k) {
        float4 a = *(const float4*)&Ast[k][ty * 4];
        float4 b = *(const float4*)&Bs[k][tx * 4];
        acc[0][0] += a.x * b.x; acc[0][1] += a.x * b.y; acc[0][2] += a.x * b.z; acc[0][3] += a.x * b.w;
        acc[1][0] += a.y * b.x; acc[1][1] += a.y * b.y; acc[1][2] += a.y * b.z; acc[1][3] += a.y * b.w;
        acc[2][0] += a.z * b.x; acc[2][1] += a.z * b.y; acc[2][2] += a.z * b.z; acc[2][3] += a.z * b.w;
        acc[3][0] += a.w * b.x; acc[3][1] += a.w * b.y; acc[3][2] += a.w * b.z; acc[3][3] += a.w * b.w;
    }

    float4 bv = *(const float4*)&bias[tx * 4];
    float4* out4 = (float4*)out;
#pragma unroll
    for (int m = 0; m < 4; ++m) {
        int r = r0 + ty * 4 + m;
        if (r < n) {
            float4 o;
            o.x = acc[m][0] + bv.x; o.y = acc[m][1] + bv.y;
            o.z = acc[m][2] + bv.z; o.w = acc[m][3] + bv.w;
            out4[r * 16 + tx] = o;
        }
    }
}

extern "C" void kernel_launch(void* const* d_in, const int* in_sizes, int n_in,
                              void* d_out, int out_size, void* d_ws, size_t ws_size,
                              hipStream_t stream) {
    const float* x    = (const float*)d_in[0];
    const int*   ei   = (const int*)d_in[1];   // [2*E] flat: rows then cols
    const float* ew   = (const float*)d_in[2];
    const float* W    = (const float*)d_in[3];
    const float* bias = (const float*)d_in[4];
    float* out = (float*)d_out;

    int n  = in_sizes[0] / D;   // 100000
    int nE = in_sizes[2];       // 1000000
    const int* rowi = ei;
    const int* coli = ei + nE;

    // workspace layout (8B-aligned first): ~10.4 MB total
    char* w = (char*)d_ws;
    int2*  scw     = (int2*)w;              w += (size_t)nE * sizeof(int2);
    float* deg     = (float*)w;             w += (size_t)n * sizeof(float);
    float* dis     = (float*)w;             w += (size_t)n * sizeof(float);
    int*   cnt     = (int*)w;               w += (size_t)n * sizeof(int);
    int*   startA  = (int*)w;               w += (size_t)n * sizeof(int);
    int*   pos     = (int*)w;               w += (size_t)n * sizeof(int);
    int*   counter = (int*)w;

    int gn  = (n + 255) / 256;
    int gE  = (nE + 255) / 256;

    k_init   <<<gn, 256, 0, stream>>>(deg, cnt, counter, n);
    k_count  <<<gE, 256, 0, stream>>>(rowi, ew, deg, cnt, nE);
    k_dis_seg<<<gn, 256, 0, stream>>>(deg, dis, cnt, startA, pos, counter, n);
    k_place  <<<gE, 256, 0, stream>>>(rowi, coli, ew, dis, pos, scw, nE);
    k_gather <<<(n * 16 + 255) / 256, 256, 0, stream>>>(x, deg, dis, startA, cnt, scw, out, n);
    gcn_gemm <<<(n + 63) / 64, 256, 0, stream>>>(out, W, bias, out, n);
}

// Round 3
// 254.009 us; speedup vs baseline: 4.0701x; 1.3537x over previous
//
#include <hip/hip_runtime.h>
#include <hip/hip_bf16.h>

#define D 64   // D_IN == D_OUT == 64

// ---------------------------------------------------------------------------
// k1: packed[i]=0 (cnt=0, deg_fixed=0), counter=0
__global__ __launch_bounds__(256) void k_init(unsigned long long* __restrict__ packed,
                                              int* __restrict__ counter, int n) {
    int i = blockIdx.x * 256 + threadIdx.x;
    if (i < n) packed[i] = 0ULL;
    if (i == 0) *counter = 0;
}

// k2: ONE 64-bit atomic per edge. high 20 bits = edge count, low 44 bits =
// fixed-point (2^-32) sum of ew. Returned old value gives this edge's rank
// within its row for free -> atomic-free placement later.
__global__ __launch_bounds__(256) void k_count(const int* __restrict__ rowi,
                                               const float* __restrict__ ew,
                                               unsigned long long* __restrict__ packed,
                                               int* __restrict__ rank, int nE) {
    int e = blockIdx.x * 256 + threadIdx.x;
    if (e < nE) {
        unsigned long long fx = (unsigned long long)((double)ew[e] * 4294967296.0);
        unsigned long long old = atomicAdd(&packed[rowi[e]], (1ULL << 44) | fx);
        rank[e] = (int)(old >> 44);
    }
}

// k3: unpack deg (+1.0 self-loop), dis=rsqrt(deg); CSR segment assignment via
// wave-scan -> one atomic per wave.
__global__ __launch_bounds__(256) void k_dis_seg(const unsigned long long* __restrict__ packed,
                                                 float* __restrict__ deg,
                                                 float* __restrict__ dis,
                                                 int* __restrict__ cnt,
                                                 int* __restrict__ start,
                                                 int* __restrict__ counter, int n) {
    int i = blockIdx.x * 256 + threadIdx.x;
    int lane = threadIdx.x & 63;
    unsigned long long p = (i < n) ? packed[i] : 0ULL;
    int c = (int)(p >> 44);
    float dg = (float)(1.0 + (double)(p & ((1ULL << 44) - 1)) * (1.0 / 4294967296.0));
    if (i < n) {
        deg[i] = dg;
        dis[i] = rsqrtf(dg);
        cnt[i] = c;
    }
    int incl = c;
#pragma unroll
    for (int o = 1; o < 64; o <<= 1) {
        int t = __shfl_up(incl, o, 64);
        if (lane >= o) incl += t;
    }
    int total = __shfl(incl, 63, 64);
    int base = 0;
    if (lane == 0) base = atomicAdd(counter, total);
    base = __shfl(base, 0, 64);
    if (i < n) start[i] = base + incl - c;
}

// k4: atomic-free placement: p = start[row] + rank[e]; pack (col, ew*dis[col]).
__global__ __launch_bounds__(256) void k_place(const int* __restrict__ rowi,
                                               const int* __restrict__ coli,
                                               const float* __restrict__ ew,
                                               const float* __restrict__ dis,
                                               const int* __restrict__ start,
                                               const int* __restrict__ rank,
                                               int2* __restrict__ scw, int nE) {
    int e = blockIdx.x * 256 + threadIdx.x;
    if (e < nE) {
        int c = coli[e];
        int p = start[rowi[e]] + rank[e];
        scw[p] = make_int2(c, __float_as_int(ew[e] * dis[c]));
    }
}

// k5: gather-aggregate, 16 lanes/node, float4 channel-slice per lane.
// The 16 lanes batch-load 16 edge descriptors in one instruction, then an
// unrolled shuffle loop issues up to 16 INDEPENDENT x-row loads (deep ILP).
__global__ __launch_bounds__(256) void k_gather(const float* __restrict__ x,
                                                const float* __restrict__ deg,
                                                const float* __restrict__ dis,
                                                const int* __restrict__ start,
                                                const int* __restrict__ cnt,
                                                const int2* __restrict__ scw,
                                                float* __restrict__ agg, int n) {
    int g = blockIdx.x * 256 + threadIdx.x;
    int i = g >> 4;
    if (i >= n) return;
    int j = g & 15;

    const float4* x4 = (const float4*)x;
    float4 acc = make_float4(0.f, 0.f, 0.f, 0.f);

    int s = start[i];
    int e_end = s + cnt[i];
    for (int e = s; e < e_end; e += 16) {
        int idx = e + j;                       // lane j prefetches edge e+j
        int2 v = make_int2(0, 0);
        if (idx < e_end) v = scw[idx];
        int m = e_end - e; if (m > 16) m = 16; // uniform within 16-lane group
#pragma unroll
        for (int t = 0; t < 16; ++t) {
            if (t < m) {
                int col = __shfl(v.x, t, 16);
                float w = __int_as_float(__shfl(v.y, t, 16));
                float4 xv = x4[col * 16 + j];
                acc.x += w * xv.x; acc.y += w * xv.y;
                acc.z += w * xv.z; acc.w += w * xv.w;
            }
        }
    }

    float di  = dis[i];
    float inv = 1.0f / deg[i];                 // self-loop: dis[i]*1*dis[i]
    float4 xs = x4[i * 16 + j];
    float4 o;
    o.x = xs.x * inv + di * acc.x;
    o.y = xs.y * inv + di * acc.y;
    o.z = xs.z * inv + di * acc.z;
    o.w = xs.w * inv + di * acc.w;
    ((float4*)agg)[i * 16 + j] = o;
}

// k6: out = agg @ W^T + bias, 64-row tile/block, 4x4 register blocking.
// IN-PLACE safe (agg == out): block stages its 64 rows through LDS first.
__global__ __launch_bounds__(256) void gcn_gemm(const float* __restrict__ agg,
                                                const float* __restrict__ W,
                                                const float* __restrict__ bias,
                                                float* __restrict__ out, int n) {
    __shared__ float Ast[D][68];  // 68: max 2-way bank aliasing (free)
    __shared__ float Bs[D][68];
    int tid = threadIdx.x;
    int r0 = blockIdx.x * 64;

    const float4* W4 = (const float4*)W;
    const float4* A4 = (const float4*)agg;
#pragma unroll
    for (int v = 0; v < 4; ++v) {
        int idx = tid + v * 256;
        int a = idx >> 4;
        int k0 = (idx & 15) * 4;
        float4 wv = W4[idx];
        Bs[k0 + 0][a] = wv.x; Bs[k0 + 1][a] = wv.y;
        Bs[k0 + 2][a] = wv.z; Bs[k0 + 3][a] = wv.w;
        int ra = r0 + a;
        float4 av = make_float4(0.f, 0.f, 0.f, 0.f);
        if (ra < n) av = A4[ra * 16 + (idx & 15)];
        Ast[k0 + 0][a] = av.x; Ast[k0 + 1][a] = av.y;
        Ast[k0 + 2][a] = av.z; Ast[k0 + 3][a] = av.w;
    }
    __syncthreads();

    int ty = tid >> 4;
    int tx = tid & 15;
    float acc[4][4];
#pragma unroll
    for (int m = 0; m < 4; ++m)
#pragma unroll
        for (int q = 0; q < 4; ++q) acc[m][q] = 0.f;

#pragma unroll
    for (int k = 0; k < D; ++k) {
        float4 a = *(const float4*)&Ast[k][ty * 4];
        float4 b = *(const float4*)&Bs[k][tx * 4];
        acc[0][0] += a.x * b.x; acc[0][1] += a.x * b.y; acc[0][2] += a.x * b.z; acc[0][3] += a.x * b.w;
        acc[1][0] += a.y * b.x; acc[1][1] += a.y * b.y; acc[1][2] += a.y * b.z; acc[1][3] += a.y * b.w;
        acc[2][0] += a.z * b.x; acc[2][1] += a.z * b.y; acc[2][2] += a.z * b.z; acc[2][3] += a.z * b.w;
        acc[3][0] += a.w * b.x; acc[3][1] += a.w * b.y; acc[3][2] += a.w * b.z; acc[3][3] += a.w * b.w;
    }

    float4 bv = *(const float4*)&bias[tx * 4];
    float4* out4 = (float4*)out;
#pragma unroll
    for (int m = 0; m < 4; ++m) {
        int r = r0 + ty * 4 + m;
        if (r < n) {
            float4 o;
            o.x = acc[m][0] + bv.x; o.y = acc[m][1] + bv.y;
            o.z = acc[m][2] + bv.z; o.w = acc[m][3] + bv.w;
            out4[r * 16 + tx] = o;
        }
    }
}

extern "C" void kernel_launch(void* const* d_in, const int* in_sizes, int n_in,
                              void* d_out, int out_size, void* d_ws, size_t ws_size,
                              hipStream_t stream) {
    const float* x    = (const float*)d_in[0];
    const int*   ei   = (const int*)d_in[1];   // [2*E] flat: rows then cols
    const float* ew   = (const float*)d_in[2];
    const float* W    = (const float*)d_in[3];
    const float* bias = (const float*)d_in[4];
    float* out = (float*)d_out;

    int n  = in_sizes[0] / D;   // 100000
    int nE = in_sizes[2];       // 1000000
    const int* rowi = ei;
    const int* coli = ei + nE;

    // workspace layout (widest alignment first): ~14.4 MB
    char* w = (char*)d_ws;
    unsigned long long* packed = (unsigned long long*)w; w += (size_t)n * 8;
    int2*  scw     = (int2*)w;              w += (size_t)nE * sizeof(int2);
    int*   rank    = (int*)w;               w += (size_t)nE * sizeof(int);
    float* deg     = (float*)w;             w += (size_t)n * sizeof(float);
    float* dis     = (float*)w;             w += (size_t)n * sizeof(float);
    int*   cnt     = (int*)w;               w += (size_t)n * sizeof(int);
    int*   startA  = (int*)w;               w += (size_t)n * sizeof(int);
    int*   counter = (int*)w;

    int gn = (n + 255) / 256;
    int gE = (nE + 255) / 256;

    k_init   <<<gn, 256, 0, stream>>>(packed, counter, n);
    k_count  <<<gE, 256, 0, stream>>>(rowi, ew, packed, rank, nE);
    k_dis_seg<<<gn, 256, 0, stream>>>(packed, deg, dis, cnt, startA, counter, n);
    k_place  <<<gE, 256, 0, stream>>>(rowi, coli, ew, dis, startA, rank, scw, nE);
    k_gather <<<(n * 16 + 255) / 256, 256, 0, stream>>>(x, deg, dis, startA, cnt, scw, out, n);
    gcn_gemm <<<(n + 63) / 64, 256, 0, stream>>>(out, W, bias, out, n);
}